// Round 1
// baseline (1371.961 us; speedup 1.0000x reference)
//
#include <hip/hip_runtime.h>
#include <math.h>

// ---------------------------------------------------------------------------
// VQ-VAE encoder, fp32 direct convolutions.
// Layout NCHW everywhere. Workspace:
//   A = ws[0 .. 16777216)        : [16,64,128,128] then reused as [16,128,64,64]
//   B = ws[16777216 .. 25165824) : [16,128,64,64]  then reused as [16,32,64,64]
// ---------------------------------------------------------------------------

__global__ __launch_bounds__(256) void conv1_k(
    const float* __restrict__ x, const float* __restrict__ w,
    const float* __restrict__ b, float* __restrict__ out)
{
    int tid = blockIdx.x * 256 + threadIdx.x;     // 16*128*128 = 262144
    int n   = tid >> 14;
    int rem = tid & 16383;
    int oy  = rem >> 7;
    int ox  = rem & 127;
    int iy0 = oy * 2 - 1, ix0 = ox * 2 - 1;
    const float* xb = x + n * 65536;
    float v[16];
#pragma unroll
    for (int ky = 0; ky < 4; ky++) {
#pragma unroll
        for (int kx = 0; kx < 4; kx++) {
            int iy = iy0 + ky, ix = ix0 + kx;
            bool ok = (iy >= 0) & (iy < 256) & (ix >= 0) & (ix < 256);
            v[ky * 4 + kx] = ok ? xb[iy * 256 + ix] : 0.f;
        }
    }
    int obase = (n * 64) * 16384 + (oy << 7) + ox;
    for (int oc = 0; oc < 64; oc++) {
        float acc = b[oc];
        const float* wp = w + oc * 16;
#pragma unroll
        for (int k = 0; k < 16; k++) acc = fmaf(v[k], wp[k], acc);
        out[obase + oc * 16384] = fmaxf(acc, 0.f);   // relu
    }
}

// conv2: [16,64,128,128] -> [16,128,64,64], 4x4 s2 p1, relu at output.
__global__ __launch_bounds__(256) void conv2_k(
    const float* __restrict__ in, const float* __restrict__ w,
    const float* __restrict__ b, float* __restrict__ out)
{
    int tid = blockIdx.x * 256 + threadIdx.x;     // 16*64*64 = 65536
    int n   = tid >> 12;
    int rem = tid & 4095;
    int oy  = rem >> 6;
    int ox  = rem & 63;
    int ocb = blockIdx.y * 32;                    // uniform -> scalar weight loads
    int iy0 = oy * 2 - 1, ix0 = ox * 2 - 1;
    int  off[16];
    bool ok[16];
#pragma unroll
    for (int ky = 0; ky < 4; ky++) {
#pragma unroll
        for (int kx = 0; kx < 4; kx++) {
            int iy = iy0 + ky, ix = ix0 + kx;
            ok[ky * 4 + kx]  = (iy >= 0) & (iy < 128) & (ix >= 0) & (ix < 128);
            off[ky * 4 + kx] = iy * 128 + ix;
        }
    }
    const float* inb = in + n * 64 * 16384;
    float acc[32];
#pragma unroll
    for (int j = 0; j < 32; j++) acc[j] = b[ocb + j];
    for (int ic = 0; ic < 64; ic++) {
        const float* p = inb + ic * 16384;
        float v[16];
#pragma unroll
        for (int k = 0; k < 16; k++) v[k] = ok[k] ? p[off[k]] : 0.f;
        const float* wic = w + ocb * 1024 + ic * 16;   // w[(oc)*64*16 + ic*16]
#pragma unroll
        for (int j = 0; j < 32; j++) {
            const float* wj = wic + j * 1024;
#pragma unroll
            for (int k = 0; k < 16; k++) acc[j] = fmaf(v[k], wj[k], acc[j]);
        }
    }
    int ob = (n * 128 + ocb) * 4096 + rem;
#pragma unroll
    for (int j = 0; j < 32; j++) out[ob + j * 4096] = fmaxf(acc[j], 0.f);
}

// conv3: [16,128,64,64] -> [16,128,64,64], 3x3 s1 p1, NO relu.
__global__ __launch_bounds__(256) void conv3_k(
    const float* __restrict__ in, const float* __restrict__ w,
    const float* __restrict__ b, float* __restrict__ out)
{
    int tid = blockIdx.x * 256 + threadIdx.x;     // 65536
    int n   = tid >> 12;
    int rem = tid & 4095;
    int oy  = rem >> 6;
    int ox  = rem & 63;
    int ocb = blockIdx.y * 32;
    int  off[9];
    bool ok[9];
#pragma unroll
    for (int ky = 0; ky < 3; ky++) {
#pragma unroll
        for (int kx = 0; kx < 3; kx++) {
            int iy = oy - 1 + ky, ix = ox - 1 + kx;
            ok[ky * 3 + kx]  = (iy >= 0) & (iy < 64) & (ix >= 0) & (ix < 64);
            off[ky * 3 + kx] = (iy << 6) + ix;
        }
    }
    const float* inb = in + n * 128 * 4096;
    float acc[32];
#pragma unroll
    for (int j = 0; j < 32; j++) acc[j] = b[ocb + j];
    for (int ic = 0; ic < 128; ic++) {
        const float* p = inb + ic * 4096;
        float v[9];
#pragma unroll
        for (int k = 0; k < 9; k++) v[k] = ok[k] ? p[off[k]] : 0.f;
        const float* wic = w + (ocb * 128 + ic) * 9;
#pragma unroll
        for (int j = 0; j < 32; j++) {
            const float* wj = wic + j * 1152;
#pragma unroll
            for (int k = 0; k < 9; k++) acc[j] = fmaf(v[k], wj[k], acc[j]);
        }
    }
    int ob = (n * 128 + ocb) * 4096 + rem;
#pragma unroll
    for (int j = 0; j < 32; j++) out[ob + j * 4096] = acc[j];
}

// residual 3x3: relu(in) conv, 128 -> 32 channels, p1, NO relu at output.
__global__ __launch_bounds__(256) void res3_k(
    const float* __restrict__ in, const float* __restrict__ w,
    const float* __restrict__ b, float* __restrict__ out)
{
    int tid = blockIdx.x * 256 + threadIdx.x;     // 65536
    int n   = tid >> 12;
    int rem = tid & 4095;
    int oy  = rem >> 6;
    int ox  = rem & 63;
    int ocb = blockIdx.y * 16;
    int  off[9];
    bool ok[9];
#pragma unroll
    for (int ky = 0; ky < 3; ky++) {
#pragma unroll
        for (int kx = 0; kx < 3; kx++) {
            int iy = oy - 1 + ky, ix = ox - 1 + kx;
            ok[ky * 3 + kx]  = (iy >= 0) & (iy < 64) & (ix >= 0) & (ix < 64);
            off[ky * 3 + kx] = (iy << 6) + ix;
        }
    }
    const float* inb = in + n * 128 * 4096;
    float acc[16];
#pragma unroll
    for (int j = 0; j < 16; j++) acc[j] = b[ocb + j];
    for (int ic = 0; ic < 128; ic++) {
        const float* p = inb + ic * 4096;
        float v[9];
#pragma unroll
        for (int k = 0; k < 9; k++) v[k] = ok[k] ? fmaxf(p[off[k]], 0.f) : 0.f;
        const float* wic = w + (ocb * 128 + ic) * 9;
#pragma unroll
        for (int j = 0; j < 16; j++) {
            const float* wj = wic + j * 1152;
#pragma unroll
            for (int k = 0; k < 9; k++) acc[j] = fmaf(v[k], wj[k], acc[j]);
        }
    }
    int ob = (n * 32 + ocb) * 4096 + rem;
#pragma unroll
    for (int j = 0; j < 16; j++) out[ob + j * 4096] = acc[j];
}

// residual 1x1: h += conv1x1(relu(t)) + bias.  t:[16,32,64,64], h:[16,128,64,64]
__global__ __launch_bounds__(256) void res1x1_k(
    const float* __restrict__ t, const float* __restrict__ w,
    const float* __restrict__ b, float* __restrict__ h)
{
    int tid = blockIdx.x * 256 + threadIdx.x;     // 65536
    int n   = tid >> 12;
    int pos = tid & 4095;
    int ocb = blockIdx.y * 32;
    const float* tb = t + n * 32 * 4096 + pos;
    float v[32];
#pragma unroll
    for (int ic = 0; ic < 32; ic++) v[ic] = fmaxf(tb[ic * 4096], 0.f);
    float* hb = h + (n * 128 + ocb) * 4096 + pos;
#pragma unroll
    for (int j = 0; j < 32; j++) {
        float acc = b[ocb + j];
        const float* wj = w + (ocb + j) * 32;
#pragma unroll
        for (int ic = 0; ic < 32; ic++) acc = fmaf(v[ic], wj[ic], acc);
        hb[j * 4096] += acc;
    }
}

// fused: z = conv1x1(relu(h), wpre) + bpre ; cosine-sim VQ ; out = codebook[idx]
__global__ __launch_bounds__(256) void prevq_k(
    const float* __restrict__ h, const float* __restrict__ wpre,
    const float* __restrict__ bpre, const float* __restrict__ cb,
    float* __restrict__ out)
{
    __shared__ float4 en[2048];                   // normalized codebook, 32 KB
    for (int i = threadIdx.x; i < 2048; i += 256) {
        float c0 = cb[i * 4 + 0], c1 = cb[i * 4 + 1];
        float c2 = cb[i * 4 + 2], c3 = cb[i * 4 + 3];
        float nrm = sqrtf(c0 * c0 + c1 * c1 + c2 * c2 + c3 * c3) + 1e-12f;
        en[i] = make_float4(c0 / nrm, c1 / nrm, c2 / nrm, c3 / nrm);
    }
    __syncthreads();

    int tid = blockIdx.x * 256 + threadIdx.x;     // 65536
    int n   = tid >> 12;
    int pos = tid & 4095;
    const float* hb = h + n * 128 * 4096 + pos;
    float z0 = bpre[0], z1 = bpre[1], z2 = bpre[2], z3 = bpre[3];
    for (int ic = 0; ic < 128; ic++) {
        float v = fmaxf(hb[ic * 4096], 0.f);
        z0 = fmaf(v, wpre[ic],       z0);
        z1 = fmaf(v, wpre[128 + ic], z1);
        z2 = fmaf(v, wpre[256 + ic], z2);
        z3 = fmaf(v, wpre[384 + ic], z3);
    }
    float nrm = sqrtf(z0 * z0 + z1 * z1 + z2 * z2 + z3 * z3) + 1e-12f;
    z0 /= nrm; z1 /= nrm; z2 /= nrm; z3 /= nrm;

    float best = -1e30f;
    int   bidx = 0;
    for (int k = 0; k < 2048; k++) {
        float4 e = en[k];
        float s = z0 * e.x + z1 * e.y + z2 * e.z + z3 * e.w;
        if (s > best) { best = s; bidx = k; }     // strict > => first max (jnp.argmax)
    }
    const float* q = cb + bidx * 4;               // raw (un-normalized) code
    out[(n * 4 + 0) * 4096 + pos] = q[0];
    out[(n * 4 + 1) * 4096 + pos] = q[1];
    out[(n * 4 + 2) * 4096 + pos] = q[2];
    out[(n * 4 + 3) * 4096 + pos] = q[3];
}

extern "C" void kernel_launch(void* const* d_in, const int* in_sizes, int n_in,
                              void* d_out, int out_size, void* d_ws, size_t ws_size,
                              hipStream_t stream)
{
    const float* x    = (const float*)d_in[0];
    const float* w1   = (const float*)d_in[1];
    const float* b1   = (const float*)d_in[2];
    const float* w2   = (const float*)d_in[3];
    const float* b2   = (const float*)d_in[4];
    const float* w3   = (const float*)d_in[5];
    const float* b3   = (const float*)d_in[6];
    const float* r1w1 = (const float*)d_in[7];
    const float* r1b1 = (const float*)d_in[8];
    const float* r1w2 = (const float*)d_in[9];
    const float* r1b2 = (const float*)d_in[10];
    const float* r2w1 = (const float*)d_in[11];
    const float* r2b1 = (const float*)d_in[12];
    const float* r2w2 = (const float*)d_in[13];
    const float* r2b2 = (const float*)d_in[14];
    const float* wpre = (const float*)d_in[15];
    const float* bpre = (const float*)d_in[16];
    const float* cb   = (const float*)d_in[17];
    float* out = (float*)d_out;

    float* A = (float*)d_ws;          // 16777216 floats
    float* B = A + 16777216;          //  8388608 floats

    conv1_k  <<<1024,        256, 0, stream>>>(x, w1, b1, A);
    conv2_k  <<<dim3(256,4), 256, 0, stream>>>(A, w2, b2, B);
    conv3_k  <<<dim3(256,4), 256, 0, stream>>>(B, w3, b3, A);
    // residual block 1
    res3_k   <<<dim3(256,2), 256, 0, stream>>>(A, r1w1, r1b1, B);
    res1x1_k <<<dim3(256,4), 256, 0, stream>>>(B, r1w2, r1b2, A);
    // residual block 2
    res3_k   <<<dim3(256,2), 256, 0, stream>>>(A, r2w1, r2b1, B);
    res1x1_k <<<dim3(256,4), 256, 0, stream>>>(B, r2w2, r2b2, A);
    // 1x1 projection + vector quantization, fused
    prevq_k  <<<256,         256, 0, stream>>>(A, wpre, bpre, cb, out);
}